// Round 8
// baseline (145.270 us; speedup 1.0000x reference)
//
#include <hip/hip_runtime.h>
#include <cstdint>

#define Bq 16
#define Nq 512
#define Dq 12
#define HID 32
#define HEADS 4
#define Cq 8
#define LOG2E 1.44269504088896f

// ws layout (float offsets)
#define OFF_G     0u         // [b][n][32]       262144
#define OFF_AS    262144u    // [b][n][4]         32768  (pre-scaled by log2e)
#define OFF_AD    294912u    // [b][n][4]         32768  (pre-scaled by log2e)
#define OFF_TIT   327680u    // [b][h][n]        262144  (ti, h-major)
#define OFF_TJBT  589824u    // [b][n][h]        262144  (tj+b1, n-major)
#define OFF_PACK  851968u    // u32 maskT [b][j][16]  (bit i>>4 of word i&15 = adj[i][j])

// ---- k0: per-node h, g, a_s, a_d. 8 nodes/block. ----
__global__ __launch_bounds__(256) void k0_node(
    const float* __restrict__ x, const float* __restrict__ Wp, const float* __restrict__ bp,
    const float* __restrict__ Wg, const float* __restrict__ att_src,
    const float* __restrict__ att_dst, float* __restrict__ ws) {
    __shared__ float xs[8 * Dq];
    __shared__ float hs[8][HID];
    int n_sub = threadIdx.x >> 5;
    int k = threadIdx.x & 31;
    int node0 = blockIdx.x * 8;
    if (threadIdx.x < 8 * Dq) xs[threadIdx.x] = x[(size_t)node0 * Dq + threadIdx.x];
    __syncthreads();
    float s = bp[k];
#pragma unroll
    for (int d = 0; d < Dq; d++) s = fmaf(Wp[k * Dq + d], xs[n_sub * Dq + d], s);
    hs[n_sub][k] = s > 0.f ? s : 0.f;
    __syncthreads();
    float g = 0.f;
#pragma unroll
    for (int d = 0; d < HID; d++) g = fmaf(Wg[k * HID + d], hs[n_sub][d], g);
    int nid = node0 + n_sub;
    ws[OFF_G + (size_t)nid * HID + k] = g;
    float ss = g * att_src[k];   // k = h*8+c
    float sd = g * att_dst[k];
#pragma unroll
    for (int off = 1; off < 8; off <<= 1) {
        ss += __shfl_xor(ss, off);
        sd += __shfl_xor(sd, off);
    }
    if ((k & 7) == 0) {
        int h = k >> 3;
        // pre-scale by log2e: k1's exp becomes a bare v_exp_f32 (verified r5)
        ws[OFF_AS + (size_t)nid * HEADS + h] = ss * LOG2E;
        ws[OFF_AD + (size_t)nid * HEADS + h] = sd * LOG2E;
    }
}

// ---- k1_fused: NO LDS staging — G/AS are L2-resident broadcasts, read direct. ----
// grid (64, Bq), block 256, 4 blocks/CU. jl = t&7 (owns j), ig = t>>3 (i ≡ ig mod 32).
// Zero main-loop barriers; adj rows hoisted to 16 regs upfront. Epilogue = r7 verbatim.
__global__ __launch_bounds__(256, 4) void k1_fused(
    const int* __restrict__ adj, const float* __restrict__ bias_g,
    const float* __restrict__ W1, const float* __restrict__ b1,
    float* __restrict__ ws) {
    int b = blockIdx.y;
    int j0 = blockIdx.x * 8;
    int t = threadIdx.x;
    int jl = t & 7;
    int ig = t >> 3;          // 0..31
    int par = ig >> 4;        // mask bit parity
    int j = j0 + jl;

    __shared__ float smem[4448];
    // epilogue regions (only read after the barrier):
    float* red = smem;            // 36×8×5 = 1440
    float* hgs = smem + 1440;     // 8×36   = 288
    float* W1s = smem + 1728;     // 32×68  = 2176
    float* tjs = smem + 3904;     // 32×9   = 288
    uint32_t* mskp = (uint32_t*)(smem + 4192);  // 256 u32

    float4 adv = *(const float4*)(ws + OFF_AD + ((size_t)b * Nq + j) * HEADS);
    const float* Gb = ws + OFF_G + (size_t)b * Nq * HID;
    const float* Ab = ws + OFF_AS + (size_t)b * Nq * HEADS;

    {   // stage W1 now (nothing reads W1s until after the barrier; overlaps main loop)
        const float4* src = (const float4*)W1;  // 512 float4
        for (int k = t; k < 512; k += 256) {
            int h = k >> 4, q = k & 15;
            *(float4*)&W1s[h * 68 + q * 4] = src[k];
        }
    }

    // hoist all 16 adjacency values (strided HBM reads, one-time latency)
    const int* adjp = adj + ((size_t)b * Nq + ig) * Nq + j;
    int areg[16];
#pragma unroll
    for (int m = 0; m < 16; m++) areg[m] = adjp[(size_t)(32 * m) * Nq];

    float lsum[HEADS] = {0.f, 0.f, 0.f, 0.f};
    float acc[HEADS][Cq] = {};
    uint32_t mask = 0;

#pragma unroll 2
    for (int m = 0; m < 16; m++) {
        int i = 32 * m + ig;
        bool on = (areg[m] != 0);
        bool msk = on || (i == j);
        mask |= (uint32_t)on << (2 * m + par);   // word ig&15, bit i>>4 = 2m+par
        float4 asv = *(const float4*)(Ab + (size_t)i * HEADS);   // L2 broadcast
        const float4* gr4 = (const float4*)(Gb + (size_t)i * HID);
        float zs[HEADS] = {asv.x + adv.x, asv.y + adv.y, asv.z + adv.z, asv.w + adv.w};
#pragma unroll
        for (int h = 0; h < HEADS; h++) {
            float z = zs[h];
            float lk = fmaxf(z, 0.2f * z);                       // leaky (log2 domain)
            float e = msk ? __builtin_amdgcn_exp2f(lk) : 0.f;    // no max-shift: |z| small
            lsum[h] += e;
            float4 g0 = gr4[2 * h];                              // L2 broadcast
            float4 g1 = gr4[2 * h + 1];
            acc[h][0] = fmaf(e, g0.x, acc[h][0]);
            acc[h][1] = fmaf(e, g0.y, acc[h][1]);
            acc[h][2] = fmaf(e, g0.z, acc[h][2]);
            acc[h][3] = fmaf(e, g0.w, acc[h][3]);
            acc[h][4] = fmaf(e, g1.x, acc[h][4]);
            acc[h][5] = fmaf(e, g1.y, acc[h][5]);
            acc[h][6] = fmaf(e, g1.z, acc[h][6]);
            acc[h][7] = fmaf(e, g1.w, acc[h][7]);
        }
    }

    // mask partials: two threads (par=0/1) cover even/odd bits of word ig&15
    mskp[par * 128 + jl * 16 + (ig & 15)] = mask;

    __syncthreads();   // mskp visible; epilogue LDS usable

    if (t < 128) {   // combine parity halves + coalesced store
        int jj = t >> 4, w = t & 15;
        uint32_t word = mskp[jj * 16 + w] | mskp[128 + jj * 16 + w];
        ((uint32_t*)(ws + OFF_PACK))[((size_t)b * Nq + j0 + jj) * 16 + w] = word;
    }
    // reduce over ig: shfl over ig bits 0..2 (lane offsets 8,16,32), LDS over 4 waves
    int w = t >> 6;
    auto dump = [&](int r, float v) {
        v += __shfl_xor(v, 8);
        v += __shfl_xor(v, 16);
        v += __shfl_xor(v, 32);
        if ((t & 63) < 8) red[(r * 8 + jl) * 5 + w] = v;
    };
#pragma unroll
    for (int h = 0; h < HEADS; h++) dump(h, lsum[h]);
#pragma unroll
    for (int h = 0; h < HEADS; h++)
#pragma unroll
        for (int cc = 0; cc < Cq; cc++) dump(4 + h * 8 + cc, acc[h][cc]);
    __syncthreads();
    for (int o = t; o < 288; o += 256) {  // 36 r × 8 j totals over 4 waves
        float* pp = &red[o * 5];
        pp[4] = (pp[0] + pp[1]) + (pp[2] + pp[3]);
    }
    __syncthreads();
    {   // hg = acc/lsum + bias_g : 256 threads = 32 d × 8 j
        int d = t >> 3, jj = t & 7;
        float s = red[((4 + d) * 8 + jj) * 5 + 4];
        float l = red[((d >> 3) * 8 + jj) * 5 + 4];
        hgs[jj * 36 + d] = s * __builtin_amdgcn_rcpf(l) + bias_g[d];
    }
    __syncthreads();
    {   // W1 epilogue: thread (jl = t&7, tg = t>>3) computes h = tg for its j
        int tg = t >> 3;
        float si = 0.f, sj = 0.f;
        const float* w0 = &W1s[tg * 68];
        const float* hr = &hgs[jl * 36];
#pragma unroll
        for (int d = 0; d < HID; d++) {
            float hv = hr[d];
            si = fmaf(hv, w0[d], si);
            sj = fmaf(hv, w0[32 + d], sj);
        }
        ws[OFF_TIT + ((size_t)b * HID + tg) * Nq + j] = si;
        tjs[tg * 9 + jl] = sj + b1[tg];     // pad 9: conflict-free transpose
    }
    __syncthreads();
    {   // coalesced transposed store [b][n][h]: 256 threads = 8 j × 32 h
        int jj = t >> 5, h = t & 31;
        ws[OFF_TJBT + ((size_t)b * Nq + j0 + jj) * HID + h] = tjs[h * 9 + jj];
    }
}

// ---- k3: pairwise score, 8-i tiles, 1024 blocks, 2-j blocking. (r7 verbatim) ----
__global__ __launch_bounds__(256, 4) void k3_score(const float* __restrict__ w2_p,
                                                   const float* __restrict__ b2_p,
                                                   const float* __restrict__ ws,
                                                   float* __restrict__ out) {
    int b = blockIdx.y;
    int i0 = blockIdx.x * 8;
    int j = threadIdx.x;        // jA = j, jB = j + 256
    __shared__ float tisT[8 * 36];   // [ii][h], row pad 36
    {
        int h = threadIdx.x >> 3, ii = threadIdx.x & 7;
        tisT[ii * 36 + h] = ws[OFF_TIT + ((size_t)b * HID + h) * Nq + i0 + ii];
    }
    float4 ta[8], tb[8];
    const float* rA = ws + OFF_TJBT + ((size_t)b * Nq + j) * HID;
    const float* rB = rA + (size_t)256 * HID;
#pragma unroll
    for (int q = 0; q < 8; q++) {
        ta[q] = *(const float4*)(rA + q * 4);
        tb[q] = *(const float4*)(rB + q * 4);
    }
    float w2l[HID];
#pragma unroll
    for (int h = 0; h < HID; h++) w2l[h] = w2_p[h];
    float b2 = b2_p[0];
    const uint32_t* mrow = (const uint32_t*)(ws + OFF_PACK)
                         + ((size_t)b * Nq + j) * 16 + (i0 & 8);
    uint4 mAv[2], mBv[2];
#pragma unroll
    for (int q = 0; q < 2; q++) {
        mAv[q] = ((const uint4*)mrow)[q];
        mBv[q] = ((const uint4*)(mrow + 256 * 16))[q];
    }
    int bit = i0 >> 4;   // constant: ii<8 never crosses the 16-boundary
    __syncthreads();
#pragma unroll
    for (int ii = 0; ii < 8; ii++) {   // full unroll: all indices static
        int i = i0 + ii;
        uint32_t mA = (ii & 3) == 0 ? mAv[ii >> 2].x : (ii & 3) == 1 ? mAv[ii >> 2].y
                    : (ii & 3) == 2 ? mAv[ii >> 2].z : mAv[ii >> 2].w;
        uint32_t mB = (ii & 3) == 0 ? mBv[ii >> 2].x : (ii & 3) == 1 ? mBv[ii >> 2].y
                    : (ii & 3) == 2 ? mBv[ii >> 2].z : mBv[ii >> 2].w;
        bool onA = (((mA >> bit) & 1u) != 0) && (i != j);
        bool onB = (((mB >> bit) & 1u) != 0) && (i != j + 256);
        float sA = b2, sB = b2;
#pragma unroll
        for (int q = 0; q < 8; q++) {
            float4 tq = *(const float4*)&tisT[ii * 36 + q * 4];  // broadcast b128
#pragma unroll
            for (int e = 0; e < 4; e++) {
                float ti = (e == 0) ? tq.x : (e == 1) ? tq.y : (e == 2) ? tq.z : tq.w;
                float tjA = (e == 0) ? ta[q].x : (e == 1) ? ta[q].y : (e == 2) ? ta[q].z : ta[q].w;
                float tjB = (e == 0) ? tb[q].x : (e == 1) ? tb[q].y : (e == 2) ? tb[q].z : tb[q].w;
                float tA = ti + tjA;
                tA = tA > 0.f ? tA : 0.f;
                sA = fmaf(tA, w2l[q * 4 + e], sA);
                float tB = ti + tjB;
                tB = tB > 0.f ? tB : 0.f;
                sB = fmaf(tB, w2l[q * 4 + e], sB);
            }
        }
        float scA = __builtin_amdgcn_rcpf(1.f + __expf(-sA));
        float scB = __builtin_amdgcn_rcpf(1.f + __expf(-sB));
        out[((size_t)b * Nq + i) * Nq + j] = onA ? scA : 0.f;
        out[((size_t)b * Nq + i) * Nq + j + 256] = onB ? scB : 0.f;
    }
}

extern "C" void kernel_launch(void* const* d_in, const int* in_sizes, int n_in,
                              void* d_out, int out_size, void* d_ws, size_t ws_size,
                              hipStream_t stream) {
    const float* x       = (const float*)d_in[0];
    const int*   adj     = (const int*)d_in[1];
    const float* Wp      = (const float*)d_in[2];
    const float* bp      = (const float*)d_in[3];
    const float* Wg      = (const float*)d_in[4];
    const float* att_src = (const float*)d_in[5];
    const float* att_dst = (const float*)d_in[6];
    const float* bias_g  = (const float*)d_in[7];
    const float* W1      = (const float*)d_in[8];
    const float* b1      = (const float*)d_in[9];
    const float* w2      = (const float*)d_in[10];
    const float* b2      = (const float*)d_in[11];
    float* out = (float*)d_out;
    float* ws = (float*)d_ws;
    (void)in_sizes; (void)n_in; (void)out_size; (void)ws_size;

    k0_node<<<dim3(1024), dim3(256), 0, stream>>>(x, Wp, bp, Wg, att_src, att_dst, ws);
    k1_fused<<<dim3(Nq / 8, Bq), dim3(256), 0, stream>>>(adj, bias_g, W1, b1, ws);
    k3_score<<<dim3(64, Bq), dim3(256), 0, stream>>>(w2, b2, ws, out);
}

// Round 9
// 127.201 us; speedup vs baseline: 1.1420x; 1.1420x over previous
//
#include <hip/hip_runtime.h>
#include <cstdint>

#define Bq 16
#define Nq 512
#define Dq 12
#define HID 32
#define HEADS 4
#define Cq 8

// ws layout (float offsets)
#define OFF_G     0u         // [b][n][32]       262144
#define OFF_AS    262144u    // [b][n][4]         32768
#define OFF_AD    294912u    // [b][n][4]         32768
#define OFF_TIT   327680u    // [b][h][n]        262144  (ti, h-major)
#define OFF_TJBT  589824u    // [b][n][h]        262144  (tj+b1, n-major)
#define OFF_PACK  851968u    // u32 maskT [b][j][16]  (bit i>>4 of word i&15 = adj[i][j])

// ---- k0: per-node h, g, a_s, a_d. 8 nodes/block. (verbatim round-4) ----
__global__ __launch_bounds__(256) void k0_node(
    const float* __restrict__ x, const float* __restrict__ Wp, const float* __restrict__ bp,
    const float* __restrict__ Wg, const float* __restrict__ att_src,
    const float* __restrict__ att_dst, float* __restrict__ ws) {
    __shared__ float xs[8 * Dq];
    __shared__ float hs[8][HID];
    int n_sub = threadIdx.x >> 5;
    int k = threadIdx.x & 31;
    int node0 = blockIdx.x * 8;
    if (threadIdx.x < 8 * Dq) xs[threadIdx.x] = x[(size_t)node0 * Dq + threadIdx.x];
    __syncthreads();
    float s = bp[k];
#pragma unroll
    for (int d = 0; d < Dq; d++) s = fmaf(Wp[k * Dq + d], xs[n_sub * Dq + d], s);
    hs[n_sub][k] = s > 0.f ? s : 0.f;
    __syncthreads();
    float g = 0.f;
#pragma unroll
    for (int d = 0; d < HID; d++) g = fmaf(Wg[k * HID + d], hs[n_sub][d], g);
    int nid = node0 + n_sub;
    ws[OFF_G + (size_t)nid * HID + k] = g;
    float ss = g * att_src[k];   // k = h*8+c
    float sd = g * att_dst[k];
#pragma unroll
    for (int off = 1; off < 8; off <<= 1) {
        ss += __shfl_xor(ss, off);
        sd += __shfl_xor(sd, off);
    }
    if ((k & 7) == 0) {
        int h = k >> 3;
        ws[OFF_AS + (size_t)nid * HEADS + h] = ss;
        ws[OFF_AD + (size_t)nid * HEADS + h] = sd;
    }
}

// ---- k1_fused: softmax-aggregate + W1 epilogue. (verbatim round-4, best verified) ----
// grid (32, Bq), block 256, 2 blocks/CU. jl = t&15 (owns j), ig = t>>4.
__global__ __launch_bounds__(256, 2) void k1_fused(
    const int* __restrict__ adj, const float* __restrict__ bias_g,
    const float* __restrict__ W1, const float* __restrict__ b1,
    float* __restrict__ ws) {
    int b = blockIdx.y;
    int j0 = blockIdx.x * 16;
    int t = threadIdx.x;
    int jl = t & 15;
    int ig = t >> 4;          // 0..15
    int j = j0 + jl;

    __shared__ float smem[6176];
    // main: gs0 @0 (2304), gs1 @2304 (2304), as0 @4608 (256), as1 @4864 (256)
    float* red = smem;            // epi: 36×16×5 = 2880
    float* hgs = smem + 2880;     // epi: 16×36   = 576
    float* W1s = smem + 3456;     // epi: 32×68   = 2176
    float* tjs = smem + 5632;     // epi: 32×17   = 544

    float4 adv = *(const float4*)(ws + OFF_AD + ((size_t)b * Nq + j) * HEADS);

    const float* Gb = ws + OFF_G + (size_t)b * Nq * HID;
    const float* Ab = ws + OFF_AS + (size_t)b * Nq * HEADS;
    int ii_s = t >> 2, q_s = t & 3;   // staging coords

    float4 ga, gb2;
    float av;
    {   // chunk 0: load + write LDS before first barrier
        const float* src = Gb + (size_t)ii_s * HID + q_s * 8;
        ga = *(const float4*)src;
        gb2 = *(const float4*)(src + 4);
        av = Ab[t];
        *(float4*)&smem[ii_s * 36 + q_s * 8] = ga;
        *(float4*)&smem[ii_s * 36 + q_s * 8 + 4] = gb2;
        smem[4608 + t] = av;
    }
    const int* adjp = adj + ((size_t)b * Nq + ig) * Nq + j;
    int cur[4], nxt[4];
#pragma unroll
    for (int kk = 0; kk < 4; kk++) cur[kk] = adjp[(size_t)(16 * kk) * Nq];

    float lsum[HEADS] = {0.f, 0.f, 0.f, 0.f};
    float acc[HEADS][Cq] = {};
    uint32_t mask = 0;

    for (int c = 0; c < 8; c++) {
        __syncthreads();                    // buf c&1 ready; buf (c+1)&1 free
        const float* gsc = (c & 1) ? smem + 2304 : smem;
        const float* asc = (c & 1) ? smem + 4864 : smem + 4608;
        if (c < 7) {                        // T14: issue next-chunk loads EARLY
            const float* src = Gb + (size_t)((c + 1) * 64 + ii_s) * HID + q_s * 8;
            ga = *(const float4*)src;
            gb2 = *(const float4*)(src + 4);
            av = Ab[(c + 1) * 256 + t];
#pragma unroll
            for (int kk = 0; kk < 4; kk++)
                nxt[kk] = adjp[(size_t)(64 * (c + 1) + 16 * kk) * Nq];
        }
#pragma unroll
        for (int kk = 0; kk < 4; kk++) {
            int m = 4 * c + kk;              // i = 16m + ig
            int i = 16 * m + ig;
            int a = cur[kk];
            bool msk = (a != 0) || (i == j);
            mask |= (uint32_t)(a != 0) << m;
            int ii = 16 * kk + ig;
            float4 asv = *(const float4*)&asc[ii * 4];
            const float* gr = &gsc[ii * 36];
            float zs[HEADS] = {asv.x + adv.x, asv.y + adv.y, asv.z + adv.z, asv.w + adv.w};
#pragma unroll
            for (int h = 0; h < HEADS; h++) {
                float z = zs[h];
                float lk = z > 0.f ? z : 0.2f * z;
                float e = msk ? __expf(lk) : 0.f;   // no max-shift: |z| small
                lsum[h] += e;
                float4 g0 = *(const float4*)(gr + h * 8);
                float4 g1 = *(const float4*)(gr + h * 8 + 4);
                acc[h][0] = fmaf(e, g0.x, acc[h][0]);
                acc[h][1] = fmaf(e, g0.y, acc[h][1]);
                acc[h][2] = fmaf(e, g0.z, acc[h][2]);
                acc[h][3] = fmaf(e, g0.w, acc[h][3]);
                acc[h][4] = fmaf(e, g1.x, acc[h][4]);
                acc[h][5] = fmaf(e, g1.y, acc[h][5]);
                acc[h][6] = fmaf(e, g1.z, acc[h][6]);
                acc[h][7] = fmaf(e, g1.w, acc[h][7]);
            }
        }
        if (c < 7) {                        // T14: ds_write LATE (after compute)
            float* gsn = (c & 1) ? smem : smem + 2304;
            float* asn = (c & 1) ? smem + 4608 : smem + 4864;
            *(float4*)&gsn[ii_s * 36 + q_s * 8] = ga;
            *(float4*)&gsn[ii_s * 36 + q_s * 8 + 4] = gb2;
            asn[t] = av;
#pragma unroll
            for (int kk = 0; kk < 4; kk++) cur[kk] = nxt[kk];
        }
    }

    // transposed adjacency mask for k3: word ig, bit m
    ((uint32_t*)(ws + OFF_PACK))[((size_t)b * Nq + j) * 16 + ig] = mask;

    __syncthreads();   // main-loop LDS dead; epilogue union usable

    {   // stage W1 (row pad 64 -> 68)
        const float4* src = (const float4*)W1;  // 512 float4
        for (int k = t; k < 512; k += 256) {
            int h = k >> 4, q = k & 15;
            *(float4*)&W1s[h * 68 + q * 4] = src[k];
        }
    }
    // reduce over ig: in-wave over 4 igs (bits 4,5 of t), then LDS over 4 waves
    int w = t >> 6;
    auto dump = [&](int r, float v) {
        v += __shfl_xor(v, 16);
        v += __shfl_xor(v, 32);
        if ((t & 63) < 16) red[(r * 16 + jl) * 5 + w] = v;
    };
#pragma unroll
    for (int h = 0; h < HEADS; h++) dump(h, lsum[h]);
#pragma unroll
    for (int h = 0; h < HEADS; h++)
#pragma unroll
        for (int cc = 0; cc < Cq; cc++) dump(4 + h * 8 + cc, acc[h][cc]);
    __syncthreads();
    for (int o = t; o < 576; o += 256) {  // 36 r × 16 j totals over 4 waves
        float* p = &red[o * 5];
        p[4] = (p[0] + p[1]) + (p[2] + p[3]);
    }
    __syncthreads();
    for (int o = t; o < 512; o += 256) {  // hg = acc/lsum + bias_g
        int d = o >> 4, jj = o & 15;
        float s = red[((4 + d) * 16 + jj) * 5 + 4];
        float l = red[((d >> 3) * 16 + jj) * 5 + 4];
        hgs[jj * 36 + d] = s * __builtin_amdgcn_rcpf(l) + bias_g[d];
    }
    __syncthreads();
    {   // W1 epilogue: thread (jl, tg) computes h = tg and tg+16
        int tg = t >> 4;
        float si0 = 0.f, sj0 = 0.f, si1 = 0.f, sj1 = 0.f;
        const float* w0 = &W1s[tg * 68];
        const float* w1 = &W1s[(tg + 16) * 68];
        const float* hr = &hgs[jl * 36];
#pragma unroll
        for (int d = 0; d < HID; d++) {
            float hv = hr[d];
            si0 = fmaf(hv, w0[d], si0);
            sj0 = fmaf(hv, w0[32 + d], sj0);
            si1 = fmaf(hv, w1[d], si1);
            sj1 = fmaf(hv, w1[32 + d], sj1);
        }
        ws[OFF_TIT + ((size_t)b * HID + tg) * Nq + j] = si0;
        ws[OFF_TIT + ((size_t)b * HID + tg + 16) * Nq + j] = si1;
        tjs[tg * 17 + jl] = sj0 + b1[tg];
        tjs[(tg + 16) * 17 + jl] = sj1 + b1[tg + 16];
    }
    __syncthreads();
    for (int o = t; o < 512; o += 256) {   // coalesced transposed store [b][n][h]
        int jj = o >> 5, h = o & 31;
        ws[OFF_TJBT + ((size_t)b * Nq + j0 + jj) * HID + h] = tjs[h * 17 + jj];
    }
}

// ---- k3: pairwise score — ISOLATED change this round. ----
// 8-i tiles -> 1024 blocks = 4 blocks/CU (vs 2), w2/b2 in SGPRs (readfirstlane,
// frees ~33 VGPR so 4 waves/SIMD fits), even/odd dual accumulators (4-way chain ILP,
// adjacent-h pairs eligible for v_pk_fma_f32). grid (64, Bq), block 256.
__global__ __launch_bounds__(256, 4) void k3_score(const float* __restrict__ w2_p,
                                                   const float* __restrict__ b2_p,
                                                   const float* __restrict__ ws,
                                                   float* __restrict__ out) {
    int b = blockIdx.y;
    int i0 = blockIdx.x * 8;
    int j = threadIdx.x;        // jA = j, jB = j + 256
    __shared__ float tisT[8 * 36];   // [ii][h], row pad 36
    {
        int h = threadIdx.x >> 3, ii = threadIdx.x & 7;
        tisT[ii * 36 + h] = ws[OFF_TIT + ((size_t)b * HID + h) * Nq + i0 + ii];
    }
    float4 ta[8], tb[8];
    const float* rA = ws + OFF_TJBT + ((size_t)b * Nq + j) * HID;
    const float* rB = rA + (size_t)256 * HID;
#pragma unroll
    for (int q = 0; q < 8; q++) {
        ta[q] = *(const float4*)(rA + q * 4);
        tb[q] = *(const float4*)(rB + q * 4);
    }
    // w2/b2 are grid-uniform: pin to SGPRs
    float w2l[HID];
#pragma unroll
    for (int h = 0; h < HID; h++)
        w2l[h] = __int_as_float(__builtin_amdgcn_readfirstlane(__float_as_int(w2_p[h])));
    float b2 = __int_as_float(__builtin_amdgcn_readfirstlane(__float_as_int(b2_p[0])));
    // words needed: (i&15) = (i0&8)+ii for ii<8 -> 8 consecutive starting at i0&8
    const uint32_t* mrow = (const uint32_t*)(ws + OFF_PACK)
                         + ((size_t)b * Nq + j) * 16 + (i0 & 8);
    uint4 mAv[2], mBv[2];
#pragma unroll
    for (int q = 0; q < 2; q++) {
        mAv[q] = ((const uint4*)mrow)[q];
        mBv[q] = ((const uint4*)(mrow + 256 * 16))[q];
    }
    int bit = i0 >> 4;   // constant: ii<8 never crosses the 16-boundary
    __syncthreads();
#pragma unroll
    for (int ii = 0; ii < 8; ii++) {   // full unroll: all indices static
        int i = i0 + ii;
        uint32_t mA = (ii & 3) == 0 ? mAv[ii >> 2].x : (ii & 3) == 1 ? mAv[ii >> 2].y
                    : (ii & 3) == 2 ? mAv[ii >> 2].z : mAv[ii >> 2].w;
        uint32_t mB = (ii & 3) == 0 ? mBv[ii >> 2].x : (ii & 3) == 1 ? mBv[ii >> 2].y
                    : (ii & 3) == 2 ? mBv[ii >> 2].z : mBv[ii >> 2].w;
        bool onA = (((mA >> bit) & 1u) != 0) && (i != j);
        bool onB = (((mB >> bit) & 1u) != 0) && (i != j + 256);
        // even/odd dual accumulators: 4 independent fma chains per output pair
        float sAx = b2, sAy = 0.f, sBx = b2, sBy = 0.f;
#pragma unroll
        for (int q = 0; q < 8; q++) {
            float4 tq = *(const float4*)&tisT[ii * 36 + q * 4];  // broadcast b128
            float uA0 = fmaxf(tq.x + ta[q].x, 0.f);
            float uA1 = fmaxf(tq.y + ta[q].y, 0.f);
            float uA2 = fmaxf(tq.z + ta[q].z, 0.f);
            float uA3 = fmaxf(tq.w + ta[q].w, 0.f);
            sAx = fmaf(uA0, w2l[q * 4 + 0], sAx);
            sAy = fmaf(uA1, w2l[q * 4 + 1], sAy);
            sAx = fmaf(uA2, w2l[q * 4 + 2], sAx);
            sAy = fmaf(uA3, w2l[q * 4 + 3], sAy);
            float uB0 = fmaxf(tq.x + tb[q].x, 0.f);
            float uB1 = fmaxf(tq.y + tb[q].y, 0.f);
            float uB2 = fmaxf(tq.z + tb[q].z, 0.f);
            float uB3 = fmaxf(tq.w + tb[q].w, 0.f);
            sBx = fmaf(uB0, w2l[q * 4 + 0], sBx);
            sBy = fmaf(uB1, w2l[q * 4 + 1], sBy);
            sBx = fmaf(uB2, w2l[q * 4 + 2], sBx);
            sBy = fmaf(uB3, w2l[q * 4 + 3], sBy);
        }
        float sA = sAx + sAy;
        float sB = sBx + sBy;
        float scA = __builtin_amdgcn_rcpf(1.f + __expf(-sA));
        float scB = __builtin_amdgcn_rcpf(1.f + __expf(-sB));
        out[((size_t)b * Nq + i) * Nq + j] = onA ? scA : 0.f;
        out[((size_t)b * Nq + i) * Nq + j + 256] = onB ? scB : 0.f;
    }
}

extern "C" void kernel_launch(void* const* d_in, const int* in_sizes, int n_in,
                              void* d_out, int out_size, void* d_ws, size_t ws_size,
                              hipStream_t stream) {
    const float* x       = (const float*)d_in[0];
    const int*   adj     = (const int*)d_in[1];
    const float* Wp      = (const float*)d_in[2];
    const float* bp      = (const float*)d_in[3];
    const float* Wg      = (const float*)d_in[4];
    const float* att_src = (const float*)d_in[5];
    const float* att_dst = (const float*)d_in[6];
    const float* bias_g  = (const float*)d_in[7];
    const float* W1      = (const float*)d_in[8];
    const float* b1      = (const float*)d_in[9];
    const float* w2      = (const float*)d_in[10];
    const float* b2      = (const float*)d_in[11];
    float* out = (float*)d_out;
    float* ws = (float*)d_ws;
    (void)in_sizes; (void)n_in; (void)out_size; (void)ws_size;

    k0_node<<<dim3(1024), dim3(256), 0, stream>>>(x, Wp, bp, Wg, att_src, att_dst, ws);
    k1_fused<<<dim3(Nq / 16, Bq), dim3(256), 0, stream>>>(adj, bias_g, W1, b1, ws);
    k3_score<<<dim3(64, Bq), dim3(256), 0, stream>>>(w2, b2, ws, out);
}